// Round 3
// baseline (142.788 us; speedup 1.0000x reference)
//
// v3: fused logits+softmax (r2 resubmit; textual change only to bust any
// content-hash caching of the failed infra result)
#include <hip/hip_runtime.h>

#define T 8
#define C 512
#define HW 196
#define NSEG 16                  // n
#define NT (NSEG * T)            // 128
#define NCOL (NT * HW)           // 25088 (nt, hw) columns
#define B_TOT (NSEG * HW)        // 3136
#define NH 4
#define KK 5
#define NO 20                    // NH*KK
#define S_SPLIT 8                // channel chunks (intra-block)
#define CCH (C / S_SPLIT)        // 64 channels per chunk
#define COLS 32                  // columns per k_weights block

// ---------------------------------------------------------------------------
// Kernel 1: fused logits + 8-chunk LDS reduction + softmax -> weights.
// Block = 256 threads = 8 channel-chunks x 32 columns. Grid = 784 blocks
// (~3 blocks/CU, 12 waves/CU). Each thread: 64ch x 20o FMA into registers,
// partials land in 20 KB LDS, 128 threads finish reduce+softmax+store.
// Eliminates the 16.1 MB partial-logits global round-trip entirely.
// ---------------------------------------------------------------------------
__global__ __launch_bounds__(256) void k_weights(const float* __restrict__ x,
                                                 const float* __restrict__ W,
                                                 float* __restrict__ wgt) {
    __shared__ float plds[S_SPLIT][NO][COLS];   // 20480 B

    const int tid  = threadIdx.x;
    const int sch  = tid >> 5;                  // channel chunk 0..7
    const int j    = tid & 31;                  // column within tile
    const int idx  = blockIdx.x * COLS + j;     // flattened (nt, hw)
    const int nt   = idx / HW;
    const int hw   = idx - nt * HW;
    const int cbase = sch * CCH;

    const float* xp = x + ((size_t)nt * C + cbase) * HW + hw;

    float acc[NO];
#pragma unroll
    for (int o = 0; o < NO; ++o) acc[o] = 0.f;

    float xv[8], xn[8];
#pragma unroll
    for (int u = 0; u < 8; ++u) xv[u] = xp[u * HW];

#pragma unroll
    for (int c0 = 0; c0 < CCH; c0 += 8) {
        if (c0 + 8 < CCH) {
#pragma unroll
            for (int u = 0; u < 8; ++u) xn[u] = xp[(c0 + 8 + u) * HW];
        }
        const float* wr = W + cbase + c0;       // wave-uniform -> s_load
#pragma unroll
        for (int o = 0; o < NO; ++o) {
#pragma unroll
            for (int u = 0; u < 8; ++u)
                acc[o] = fmaf(xv[u], wr[o * C + u], acc[o]);
        }
#pragma unroll
        for (int u = 0; u < 8; ++u) xv[u] = xn[u];
    }

    // partials: [chunk][o][col] — worst case 2-way bank aliasing (free, m136)
#pragma unroll
    for (int o = 0; o < NO; ++o) plds[sch][o][j] = acc[o];
    __syncthreads();

    // reduce over chunks (same s-order as the old k_softmax -> same numerics),
    // then softmax over the 5 taps. One thread per (col, head).
    if (tid < COLS * NH) {
        const int col  = tid & 31;
        const int h    = tid >> 5;
        const int idx2 = blockIdx.x * COLS + col;
        const int nt2  = idx2 / HW;
        const int hw2  = idx2 - nt2 * HW;
        const int t    = nt2 & (T - 1);
        const int n    = nt2 / T;
        const int b    = n * HW + hw2;

        float lg[KK];
#pragma unroll
        for (int k = 0; k < KK; ++k) {
            float sm = 0.f;
#pragma unroll
            for (int s2 = 0; s2 < S_SPLIT; ++s2)
                sm += plds[s2][h * KK + k][col];
            lg[k] = sm;
        }

        float m = lg[0];
#pragma unroll
        for (int k = 1; k < KK; ++k) m = fmaxf(m, lg[k]);
        float e[KK];
        float sum = 0.f;
#pragma unroll
        for (int k = 0; k < KK; ++k) {
            e[k] = __expf(lg[k] - m);
            sum += e[k];
        }
        const float r = 1.f / sum;
#pragma unroll
        for (int k = 0; k < KK; ++k)
            wgt[((size_t)((t * NH + h) * KK + k)) * B_TOT + b] = e[k] * r;
    }
}

// ---------------------------------------------------------------------------
// Kernel 2: causal dynamic conv, one thread per (n, c, hw). Unchanged —
// already near its ~105 MB traffic floor (~17 µs @ 6.3 TB/s).
// ---------------------------------------------------------------------------
__global__ __launch_bounds__(256) void k_conv(const float* __restrict__ x,
                                              const float* __restrict__ wgt,
                                              float* __restrict__ out) {
    const int idx = blockIdx.x * 256 + threadIdx.x;  // < 16*512*196
    const int hw  = idx % HW;
    const int t1  = idx / HW;          // n*C + c
    const int c   = t1 % C;
    const int n   = t1 / C;
    const int h   = c >> 7;            // head
    const int b   = n * HW + hw;

    float w[T][KK];
#pragma unroll
    for (int t = 0; t < T; ++t)
#pragma unroll
        for (int k = 0; k < KK; ++k)
            w[t][k] = wgt[((size_t)((t * NH + h) * KK + k)) * B_TOT + b];

    const size_t base = ((size_t)(n * T) * C + c) * HW + hw;
    float xv[T];
#pragma unroll
    for (int t = 0; t < T; ++t) xv[t] = x[base + (size_t)t * C * HW];

#pragma unroll
    for (int t = 0; t < T; ++t) {
        float acc = 0.f;
#pragma unroll
        for (int k = 0; k < KK; ++k) {
            const int j = t + k - 4;   // causal, zero-padded left
            if (j >= 0) acc = fmaf(w[t][k], xv[j], acc);
        }
        out[base + (size_t)t * C * HW] = acc;
    }
}

// ---------------------------------------------------------------------------
extern "C" void kernel_launch(void* const* d_in, const int* in_sizes, int n_in,
                              void* d_out, int out_size, void* d_ws, size_t ws_size,
                              hipStream_t stream) {
    const float* x = (const float*)d_in[0];   // (128, 512, 14, 14)
    const float* W = (const float*)d_in[1];   // (20, 512)
    float* out = (float*)d_out;               // (128, 512, 14, 14)

    // workspace: only the softmaxed weights now — 160 * 3136 floats = 2 MB
    float* wgt = (float*)d_ws;

    k_weights<<<dim3(NCOL / COLS), 256, 0, stream>>>(x, W, wgt);
    k_conv<<<dim3((NSEG * C * HW) / 256), 256, 0, stream>>>(x, wgt, out);
}

// Round 4
// 116.325 us; speedup vs baseline: 1.2275x; 1.2275x over previous
//
// v4: fix W-load scalarization — chunk index must be wave-uniform.
// k_weights: 512 thr = 8 waves; wave w = channel chunk w (s_load'able W),
// 64 lanes = 64 columns; 40 KB LDS partials; fused softmax. k_conv unchanged.
#include <hip/hip_runtime.h>

#define T 8
#define C 512
#define HW 196
#define NSEG 16                  // n
#define NT (NSEG * T)            // 128
#define NCOL (NT * HW)           // 25088 (nt, hw) columns
#define B_TOT (NSEG * HW)        // 3136
#define NH 4
#define KK 5
#define NO 20                    // NH*KK
#define S_SPLIT 8                // channel chunks = waves per block
#define CCH (C / S_SPLIT)        // 64 channels per chunk
#define COLS 64                  // columns per k_weights block (= lanes)

// ---------------------------------------------------------------------------
// Kernel 1: fused logits + LDS chunk-reduction + softmax -> weights.
// Grid 392 x 512. Each wave: 64 channels x 20 outputs FMA, W via scalar
// loads (cbase is readfirstlane-pinned -> provably wave-uniform).
// ---------------------------------------------------------------------------
__global__ __launch_bounds__(512) void k_weights(const float* __restrict__ x,
                                                 const float* __restrict__ W,
                                                 float* __restrict__ wgt) {
    __shared__ float plds[S_SPLIT][NO][COLS];   // 40960 B

    const int tid  = threadIdx.x;
    const int lane = tid & 63;                  // column within tile
    const int sch  = tid >> 6;                  // wave index = channel chunk
    const int cbase = __builtin_amdgcn_readfirstlane(sch * CCH);  // SGPR

    const int idx = blockIdx.x * COLS + lane;   // flattened (nt, hw)
    const int nt  = idx / HW;
    const int hw  = idx - nt * HW;

    const float* xp = x + ((size_t)nt * C + cbase) * HW + hw;
    const float* Wb = W + cbase;                // wave-uniform base -> s_load

    float acc[NO];
#pragma unroll
    for (int o = 0; o < NO; ++o) acc[o] = 0.f;

    float xv[8], xn[8];
#pragma unroll
    for (int u = 0; u < 8; ++u) xv[u] = xp[u * HW];

#pragma unroll
    for (int c0 = 0; c0 < CCH; c0 += 8) {
        if (c0 + 8 < CCH) {
#pragma unroll
            for (int u = 0; u < 8; ++u) xn[u] = xp[(c0 + 8 + u) * HW];
        }
        const float* wr = Wb + c0;              // wave-uniform
#pragma unroll
        for (int o = 0; o < NO; ++o) {
#pragma unroll
            for (int u = 0; u < 8; ++u)
                acc[o] = fmaf(xv[u], wr[o * C + u], acc[o]);
        }
#pragma unroll
        for (int u = 0; u < 8; ++u) xv[u] = xn[u];
    }

    // partials: lane-consecutive -> 2-way bank aliasing max (free on CDNA4)
#pragma unroll
    for (int o = 0; o < NO; ++o) plds[sch][o][lane] = acc[o];
    __syncthreads();

    // reduce over chunks (same s-order as before -> identical numerics),
    // softmax over 5 taps. 256 threads: (col 0..63) x (head 0..3).
    if (tid < COLS * NH) {
        const int col  = tid & 63;
        const int h    = tid >> 6;
        const int idx2 = blockIdx.x * COLS + col;
        const int nt2  = idx2 / HW;
        const int hw2  = idx2 - nt2 * HW;
        const int t    = nt2 & (T - 1);
        const int n    = nt2 / T;
        const int b    = n * HW + hw2;

        float lg[KK];
#pragma unroll
        for (int k = 0; k < KK; ++k) {
            float sm = 0.f;
#pragma unroll
            for (int s2 = 0; s2 < S_SPLIT; ++s2)
                sm += plds[s2][h * KK + k][col];
            lg[k] = sm;
        }

        float m = lg[0];
#pragma unroll
        for (int k = 1; k < KK; ++k) m = fmaxf(m, lg[k]);
        float e[KK];
        float sum = 0.f;
#pragma unroll
        for (int k = 0; k < KK; ++k) {
            e[k] = __expf(lg[k] - m);
            sum += e[k];
        }
        const float r = 1.f / sum;
#pragma unroll
        for (int k = 0; k < KK; ++k)
            wgt[((size_t)((t * NH + h) * KK + k)) * B_TOT + b] = e[k] * r;
    }
}

// ---------------------------------------------------------------------------
// Kernel 2: causal dynamic conv, one thread per (n, c, hw). Unchanged —
// near its ~105 MB traffic floor.
// ---------------------------------------------------------------------------
__global__ __launch_bounds__(256) void k_conv(const float* __restrict__ x,
                                              const float* __restrict__ wgt,
                                              float* __restrict__ out) {
    const int idx = blockIdx.x * 256 + threadIdx.x;  // < 16*512*196
    const int hw  = idx % HW;
    const int t1  = idx / HW;          // n*C + c
    const int c   = t1 % C;
    const int n   = t1 / C;
    const int h   = c >> 7;            // head
    const int b   = n * HW + hw;

    float w[T][KK];
#pragma unroll
    for (int t = 0; t < T; ++t)
#pragma unroll
        for (int k = 0; k < KK; ++k)
            w[t][k] = wgt[((size_t)((t * NH + h) * KK + k)) * B_TOT + b];

    const size_t base = ((size_t)(n * T) * C + c) * HW + hw;
    float xv[T];
#pragma unroll
    for (int t = 0; t < T; ++t) xv[t] = x[base + (size_t)t * C * HW];

#pragma unroll
    for (int t = 0; t < T; ++t) {
        float acc = 0.f;
#pragma unroll
        for (int k = 0; k < KK; ++k) {
            const int j = t + k - 4;   // causal, zero-padded left
            if (j >= 0) acc = fmaf(w[t][k], xv[j], acc);
        }
        out[base + (size_t)t * C * HW] = acc;
    }
}

// ---------------------------------------------------------------------------
extern "C" void kernel_launch(void* const* d_in, const int* in_sizes, int n_in,
                              void* d_out, int out_size, void* d_ws, size_t ws_size,
                              hipStream_t stream) {
    const float* x = (const float*)d_in[0];   // (128, 512, 14, 14)
    const float* W = (const float*)d_in[1];   // (20, 512)
    float* out = (float*)d_out;               // (128, 512, 14, 14)

    float* wgt = (float*)d_ws;                // 160 * 3136 floats = 2 MB

    k_weights<<<dim3(NCOL / COLS), 512, 0, stream>>>(x, W, wgt);
    k_conv<<<dim3((NSEG * C * HW) / 256), 256, 0, stream>>>(x, wgt, out);
}